// Round 8
// baseline (174.294 us; speedup 1.0000x reference)
//
#include <hip/hip_runtime.h>
#include <math.h>

#define NCLS 21
#define NGT 32
#define CLIPLEN 256.0f
#define MAXN 512.0f
#define FEPS 1.1920928955078125e-07f

#define ROWF 21            // floats per class row
#define WCH (64 * ROWF)    // floats per wave chunk (64 anchors) = 1344

#define SINK(x) asm volatile("" :: "v"(x))

// partial layout in d_ws (doubles): p[i * nblk + blk], i in 0..6

__device__ __forceinline__ float fastrcp(float x) { return __builtin_amdgcn_rcpf(x); }

__device__ __forceinline__ void glds16(const float* g, float* l) {
    __builtin_amdgcn_global_load_lds(
        (const __attribute__((address_space(1))) void*)g,
        (__attribute__((address_space(3))) void*)l, 16, 0, 0);
}
__device__ __forceinline__ void glds4(const float* g, float* l) {
    __builtin_amdgcn_global_load_lds(
        (const __attribute__((address_space(1))) void*)g,
        (__attribute__((address_space(3))) void*)l, 4, 0, 0);
}

__device__ __forceinline__ void stage_rows(const float* g, float* l, int lane) {
#pragma unroll
    for (int i = 0; i < 5; ++i)
        glds16(g + i * 256 + lane * 4, l + i * 256);
    glds4(g + 1280 + lane, l + 1280);
}

__device__ __forceinline__ void load_row(const float* __restrict__ row, float* r) {
#pragma unroll
    for (int i = 0; i < NCLS; ++i) r[i] = row[i];
}

// focal with rt supplied (LDS fetch)
__device__ __forceinline__ float focal_from(const float* r, float rt, int tgt) {
    float m0 = fmaxf(fmaxf(r[0],  r[1]),  r[2]);
    float m1 = fmaxf(fmaxf(r[3],  r[4]),  r[5]);
    float m2 = fmaxf(fmaxf(r[6],  r[7]),  r[8]);
    float m3 = fmaxf(fmaxf(r[9],  r[10]), r[11]);
    float m4 = fmaxf(fmaxf(r[12], r[13]), r[14]);
    float m5 = fmaxf(fmaxf(r[15], r[16]), r[17]);
    float m6 = fmaxf(fmaxf(r[18], r[19]), r[20]);
    float ma = fmaxf(fmaxf(m0, m1), m2);
    float mb = fmaxf(fmaxf(m3, m4), m5);
    float m  = fmaxf(fmaxf(ma, mb), m6);
    float e[NCLS];
#pragma unroll
    for (int i = 0; i < NCLS; ++i) e[i] = __expf(r[i] - m);
    float s0 = (e[0] + e[1])  + (e[2] + e[3]);
    float s1 = (e[4] + e[5])  + (e[6] + e[7]);
    float s2 = (e[8] + e[9])  + (e[10] + e[11]);
    float s3 = (e[12] + e[13]) + (e[14] + e[15]);
    float s4 = (e[16] + e[17]) + (e[18] + e[19]);
    float s  = ((s0 + s1) + (s2 + s3)) + (s4 + e[20]);
    float pt  = __expf(rt - m) * fastrcp(s) + 1e-10f;
    float lpt = __logf(pt);
    float a   = (tgt == 0) ? 0.25f : 0.75f;
    float om  = 1.0f - pt;
    return -a * om * om * lpt;
}

// focal with in-loop rt select (for the no-LDS ablation)
__device__ __forceinline__ float focal_sel(const float* r, int tgt) {
    float m = r[0];
#pragma unroll
    for (int i = 1; i < NCLS; ++i) m = fmaxf(m, r[i]);
    float s = 0.0f, rt = 0.0f;
#pragma unroll
    for (int i = 0; i < NCLS; ++i) {
        s += __expf(r[i] - m);
        if (i == tgt) rt = r[i];
    }
    float pt  = __expf(rt - m) * fastrcp(s) + 1e-10f;
    float a   = (tgt == 0) ? 0.25f : 0.75f;
    float om  = 1.0f - pt;
    return -a * om * om * __logf(pt);
}

// MODE 0: full (real). 1: loads-as-real only. 2: compute only (no class loads).
// 4: per-lane strided dword loads to VGPR. 5: ideal coalesced float4 loads.
template <int MODE, bool PARTIALS>
__global__ __launch_bounds__(256, 7) void msl_main(
    const float* __restrict__ loc_data,
    const float* __restrict__ conf_data,
    const float* __restrict__ prop_loc_data,
    const float* __restrict__ prop_conf_data,
    const float* __restrict__ center_data,
    const float* __restrict__ priors,
    const float* __restrict__ targets,
    double* __restrict__ ws,
    int K, int nblk)
{
    __shared__ float s_cls[4][WCH];   // kept in ALL modes to pin occupancy
    __shared__ float s_red[6 * 4];

    const int b    = blockIdx.y;
    const int tid  = threadIdx.x;
    const int lane = tid & 63;
    const int w    = tid >> 6;
    const int kblk = blockIdx.x * 256;
    const int k    = kblk + tid;
    const size_t idx = (size_t)b * K + k;

    const size_t chunk0 = ((size_t)b * K + kblk + w * 64) * ROWF;
    float* lbuf = &s_cls[w][0];

    // small per-anchor loads (all modes)
    const float  c   = priors[k];
    const float2 loc = ((const float2*)loc_data)[idx];
    const float2 plo = ((const float2*)prop_loc_data)[idx];
    const float  x   = center_data[idx];

    if constexpr (MODE == 1) {
        // ---- loads exactly as real kernel, no compute ----
        stage_rows(conf_data + chunk0, lbuf, lane);
        asm volatile("s_waitcnt vmcnt(0)" ::: "memory");
        __builtin_amdgcn_sched_barrier(0);
        float s1 = lbuf[lane * ROWF];
        asm volatile("s_waitcnt lgkmcnt(0)" ::: "memory");
        __builtin_amdgcn_sched_barrier(0);
        stage_rows(prop_conf_data + chunk0, lbuf, lane);
        asm volatile("s_waitcnt vmcnt(0)" ::: "memory");
        __builtin_amdgcn_sched_barrier(0);
        float s2 = lbuf[lane * ROWF + 1];
        SINK(c); SINK(loc.x); SINK(loc.y); SINK(plo.x); SINK(plo.y); SINK(x);
        SINK(s1); SINK(s2);
        return;
    }

    if constexpr (MODE == 4) {
        // ---- per-lane strided dword loads straight to VGPR ----
        const float* rowc = conf_data + (chunk0 + (size_t)lane * ROWF);
        const float* rowp = prop_conf_data + (chunk0 + (size_t)lane * ROWF);
        float acc = 0.0f;
#pragma unroll
        for (int i = 0; i < NCLS; ++i) acc = fmaxf(acc, rowc[i]);
#pragma unroll
        for (int i = 0; i < NCLS; ++i) acc = fmaxf(acc, rowp[i]);
        SINK(acc); SINK(c); SINK(loc.x); SINK(plo.x); SINK(x);
        return;
    }

    if constexpr (MODE == 5) {
        // ---- ideal coalesced float4 loads of the same byte volume ----
        const float4* c4 = (const float4*)(conf_data + chunk0);
        const float4* p4 = (const float4*)(prop_conf_data + chunk0);
        float acc = 0.0f;
#pragma unroll
        for (int j = 0; j < 5; ++j) {
            float4 v = c4[lane + 64 * j];
            acc = fmaxf(fmaxf(acc, fmaxf(v.x, v.y)), fmaxf(v.z, v.w));
        }
        acc = fmaxf(acc, (conf_data + chunk0)[1280 + lane]);
#pragma unroll
        for (int j = 0; j < 5; ++j) {
            float4 v = p4[lane + 64 * j];
            acc = fmaxf(fmaxf(acc, fmaxf(v.x, v.y)), fmaxf(v.z, v.w));
        }
        acc = fmaxf(acc, (prop_conf_data + chunk0)[1280 + lane]);
        SINK(acc); SINK(c); SINK(loc.x); SINK(plo.x); SINK(x);
        return;
    }

    // MODE 0 and 2 share the compute path
    if constexpr (MODE == 0)
        stage_rows(conf_data + chunk0, lbuf, lane);

    // ---- match: argmin over 32 GTs via scalar targets ----
    const float* tgs = targets + (size_t)b * (NGT * 3);
    float bestA = 3.0e38f;
    float bT0 = 0.0f, bT1 = 0.0f, bLb = 0.0f;
#pragma unroll
    for (int n = 0; n < NGT; ++n) {
        const float t0n = tgs[3 * n];
        const float t1n = tgs[3 * n + 1];
        const float lbn = tgs[3 * n + 2];
        const bool outside = (t0n > c) || (t1n < c);
        const float cand = outside ? MAXN : (t1n - t0n) * CLIPLEN;
        const bool better = cand < bestA;
        bestA = better ? cand : bestA;
        bT0   = better ? t0n  : bT0;
        bT1   = better ? t1n  : bT1;
        bLb   = better ? lbn  : bLb;
    }
    const float tl = (c - bT0) * CLIPLEN;
    const float tr = (bT1 - c) * CLIPLEN;
    int conf_t = (bestA >= MAXN) ? 0 : (int)bLb;

    const float pl = loc.x, pr = loc.y;
    const float inter = fminf(pl, tl) + fminf(pr, tr);
    const float uni   = pl + pr + tl + tr - inter;
    const float iou   = inter * fastrcp(fmaxf(uni, FEPS));
    const int prop_conf_t = (iou < 0.5f) ? 0 : conf_t;
    const float posf = (conf_t > 0) ? 1.0f : 0.0f;
    const float ppf  = (prop_conf_t > 0) ? 1.0f : 0.0f;
    const float ac   = fmaxf(pl, tl) + fmaxf(pr, tr);
    const float giou = iou - (ac - uni) * fastrcp(fmaxf(ac, FEPS));
    const float v_ll = (1.0f - giou) * posf;
    const float prop_w = pl + pr;
    const float inv_hw = 2.0f * fastrcp(prop_w);
    const float plt0 = (tl - pl) * inv_hw;
    const float plt1 = (tr - pr) * inv_hw;
    const float v_lpl = (fabsf(plo.x - plt0) + fabsf(plo.y - plt1)) * ppf;
    const float cur0 = 0.5f * prop_w * plo.x + pl;
    const float cur1 = 0.5f * prop_w * plo.y + pr;
    const float in2  = fminf(cur0, tl) + fminf(cur1, tr);
    const float un2  = cur0 + cur1 + tl + tr - in2;
    const float iou2 = fmaxf(in2 * fastrcp(fmaxf(un2, FEPS)), 0.0f);
    const float ebx  = __expf(-fabsf(x));
    const float bce  = fmaxf(x, 0.0f) - x * iou2 + __logf(1.0f + ebx);
    const float v_ct = bce * posf;

    float v_lc, v_lpc;
    if constexpr (MODE == 2) {
        // synthetic register rows: same focal arithmetic, zero class loads
        float g0 = c * 0.37f + loc.x;
        float g1 = plo.x * 0.11f - x;
        float rr[NCLS];
#pragma unroll
        for (int i = 0; i < NCLS; ++i) rr[i] = fmaf(g0, (float)i, g1);
        v_lc  = focal_sel(rr, conf_t);
#pragma unroll
        for (int i = 0; i < NCLS; ++i) rr[i] = fmaf(g1, (float)i, g0);
        v_lpc = focal_sel(rr, prop_conf_t);
        SINK(v_ll); SINK(v_lc); SINK(v_lpl); SINK(v_lpc); SINK(v_ct);
        SINK(posf); SINK(ppf);
        return;
    } else {
        asm volatile("s_waitcnt vmcnt(0)" ::: "memory");
        __builtin_amdgcn_sched_barrier(0);
        const float* rowp = lbuf + lane * ROWF;
        float rr[NCLS];
        load_row(rowp, rr);
        const float rt_c = rowp[conf_t];
        asm volatile("s_waitcnt lgkmcnt(0)" ::: "memory");
        __builtin_amdgcn_sched_barrier(0);
        stage_rows(prop_conf_data + chunk0, lbuf, lane);
        v_lc = focal_from(rr, rt_c, conf_t);
        asm volatile("s_waitcnt vmcnt(0)" ::: "memory");
        __builtin_amdgcn_sched_barrier(0);
        load_row(rowp, rr);
        const float rt_p = rowp[prop_conf_t];
        v_lpc = focal_from(rr, rt_p, prop_conf_t);
    }

    // ---- block reduction ----
    float vals[6] = { v_ll, v_lc, v_lpl, v_lpc, v_ct, posf + 4096.0f * ppf };
#pragma unroll
    for (int i = 0; i < 6; ++i) {
        float v = vals[i];
#pragma unroll
        for (int off = 32; off > 0; off >>= 1) v += __shfl_xor(v, off);
        if (lane == 0) s_red[i * 4 + w] = v;
    }
    __syncthreads();
    if (tid == 0) {
        const int blk = blockIdx.y * gridDim.x + blockIdx.x;
#pragma unroll
        for (int i = 0; i < 5; ++i) {
            double s = (double)s_red[i * 4 + 0] + (double)s_red[i * 4 + 1]
                     + (double)s_red[i * 4 + 2] + (double)s_red[i * 4 + 3];
            if (PARTIALS) ws[(size_t)i * nblk + blk] = s;
            else          atomicAdd(&ws[i], s);
        }
        double ct = (double)s_red[5 * 4 + 0] + (double)s_red[5 * 4 + 1]
                  + (double)s_red[5 * 4 + 2] + (double)s_red[5 * 4 + 3];
        double pp = floor(ct / 4096.0);
        double ps = ct - 4096.0 * pp;
        if (PARTIALS) {
            ws[(size_t)5 * nblk + blk] = ps;
            ws[(size_t)6 * nblk + blk] = pp;
        } else {
            atomicAdd(&ws[5], ps);
            atomicAdd(&ws[6], pp);
        }
    }
}

__global__ __launch_bounds__(256) void msl_reduce(
    const double* __restrict__ p, int nblk, float* __restrict__ out)
{
    __shared__ double s_acc[7];
    __shared__ double s_w[4];
    const int tid  = threadIdx.x;
    const int lane = tid & 63;
    const int w    = tid >> 6;
    for (int i = 0; i < 7; ++i) {
        double v = 0.0;
        for (int j = tid; j < nblk; j += 256) v += p[(size_t)i * nblk + j];
#pragma unroll
        for (int off = 32; off > 0; off >>= 1) v += __shfl_xor(v, off);
        if (lane == 0) s_w[w] = v;
        __syncthreads();
        if (tid == 0) s_acc[i] = s_w[0] + s_w[1] + s_w[2] + s_w[3];
        __syncthreads();
    }
    if (tid == 0) {
        const double N  = fmax(s_acc[5], 1.0);
        const double PN = fmax(s_acc[6], 1.0);
        out[0] = (float)(s_acc[0] / N);
        out[1] = (float)(s_acc[1] / N);
        out[2] = (float)(s_acc[2] / PN);
        out[3] = (float)(s_acc[3] / PN);
        out[4] = (float)(s_acc[4] / N);
    }
}

__global__ void msl_finalize(const double* __restrict__ acc, float* __restrict__ out) {
    const double N  = fmax(acc[5], 1.0);
    const double PN = fmax(acc[6], 1.0);
    out[0] = (float)(acc[0] / N);
    out[1] = (float)(acc[1] / N);
    out[2] = (float)(acc[2] / PN);
    out[3] = (float)(acc[3] / PN);
    out[4] = (float)(acc[4] / N);
}

extern "C" void kernel_launch(void* const* d_in, const int* in_sizes, int n_in,
                              void* d_out, int out_size, void* d_ws, size_t ws_size,
                              hipStream_t stream) {
    const float* loc_data       = (const float*)d_in[0];
    const float* conf_data      = (const float*)d_in[1];
    const float* prop_loc_data  = (const float*)d_in[2];
    const float* prop_conf_data = (const float*)d_in[3];
    const float* center_data    = (const float*)d_in[4];
    const float* priors         = (const float*)d_in[5];
    const float* targets        = (const float*)d_in[6];
    float* out = (float*)d_out;

    const int K = in_sizes[5];
    const int B = in_sizes[6] / (NGT * 3);
    const int nblk = (K / 256) * B;

    double* ws = (double*)d_ws;
    dim3 grid(K / 256, B);

    if (ws_size >= (size_t)7 * nblk * sizeof(double)) {
        msl_main<0, true><<<grid, 256, 0, stream>>>(loc_data, conf_data, prop_loc_data,
                                                    prop_conf_data, center_data, priors,
                                                    targets, ws, K, nblk);
        msl_reduce<<<1, 256, 0, stream>>>(ws, nblk, out);
    } else {
        hipMemsetAsync(ws, 0, 7 * sizeof(double), stream);
        msl_main<0, false><<<grid, 256, 0, stream>>>(loc_data, conf_data, prop_loc_data,
                                                     prop_conf_data, center_data, priors,
                                                     targets, ws, K, nblk);
        msl_finalize<<<1, 1, 0, stream>>>(ws, out);
    }

    // ---- ablation dispatches (no stores; rocprof per-dispatch timing only) ----
    msl_main<1, true><<<grid, 256, 0, stream>>>(loc_data, conf_data, prop_loc_data,
                                                prop_conf_data, center_data, priors,
                                                targets, ws, K, nblk);
    msl_main<2, true><<<grid, 256, 0, stream>>>(loc_data, conf_data, prop_loc_data,
                                                prop_conf_data, center_data, priors,
                                                targets, ws, K, nblk);
    msl_main<4, true><<<grid, 256, 0, stream>>>(loc_data, conf_data, prop_loc_data,
                                                prop_conf_data, center_data, priors,
                                                targets, ws, K, nblk);
    msl_main<5, true><<<grid, 256, 0, stream>>>(loc_data, conf_data, prop_loc_data,
                                                prop_conf_data, center_data, priors,
                                                targets, ws, K, nblk);
}

// Round 9
// 69.026 us; speedup vs baseline: 2.5251x; 2.5251x over previous
//
#include <hip/hip_runtime.h>
#include <math.h>

#define NCLS 21
#define NGT 32
#define CLIPLEN 256.0f
#define MAXN 512.0f
#define FEPS 1.1920928955078125e-07f

// partial layout in d_ws (doubles): p[i * nblk + blk], i in 0..6
// i: 0 loss_l, 1 loss_c, 2 loss_prop_l, 3 loss_prop_c, 4 loss_ct, 5 pos, 6 prop_pos

typedef float f32x4 __attribute__((ext_vector_type(4)));
typedef f32x4 f32x4_u __attribute__((aligned(4)));   // dword-aligned vector load

__device__ __forceinline__ float fastrcp(float x) { return __builtin_amdgcn_rcpf(x); }

__device__ __forceinline__ void load_row21(const float* __restrict__ p, float* r) {
    // 5 x dwordx4 + 1 x dword, 4-byte aligned (hw supports dword-aligned x4)
    f32x4 v0 = *(const f32x4_u*)(p + 0);
    f32x4 v1 = *(const f32x4_u*)(p + 4);
    f32x4 v2 = *(const f32x4_u*)(p + 8);
    f32x4 v3 = *(const f32x4_u*)(p + 12);
    f32x4 v4 = *(const f32x4_u*)(p + 16);
    float  v5 = p[20];
    r[0]=v0.x; r[1]=v0.y; r[2]=v0.z; r[3]=v0.w;
    r[4]=v1.x; r[5]=v1.y; r[6]=v1.z; r[7]=v1.w;
    r[8]=v2.x; r[9]=v2.y; r[10]=v2.z; r[11]=v2.w;
    r[12]=v3.x; r[13]=v3.y; r[14]=v3.z; r[15]=v3.w;
    r[16]=v4.x; r[17]=v4.y; r[18]=v4.z; r[19]=v4.w;
    r[20]=v5;
}

// focal from register row; rt extracted with compile-time-index selects
__device__ __forceinline__ float focal_reg(const float* r, int tgt) {
    float m0 = fmaxf(fmaxf(r[0],  r[1]),  r[2]);
    float m1 = fmaxf(fmaxf(r[3],  r[4]),  r[5]);
    float m2 = fmaxf(fmaxf(r[6],  r[7]),  r[8]);
    float m3 = fmaxf(fmaxf(r[9],  r[10]), r[11]);
    float m4 = fmaxf(fmaxf(r[12], r[13]), r[14]);
    float m5 = fmaxf(fmaxf(r[15], r[16]), r[17]);
    float m6 = fmaxf(fmaxf(r[18], r[19]), r[20]);
    float ma = fmaxf(fmaxf(m0, m1), m2);
    float mb = fmaxf(fmaxf(m3, m4), m5);
    float m  = fmaxf(fmaxf(ma, mb), m6);

    float e[NCLS];
#pragma unroll
    for (int i = 0; i < NCLS; ++i) e[i] = __expf(r[i] - m);
    float s0 = (e[0] + e[1])  + (e[2] + e[3]);
    float s1 = (e[4] + e[5])  + (e[6] + e[7]);
    float s2 = (e[8] + e[9])  + (e[10] + e[11]);
    float s3 = (e[12] + e[13]) + (e[14] + e[15]);
    float s4 = (e[16] + e[17]) + (e[18] + e[19]);
    float s  = ((s0 + s1) + (s2 + s3)) + (s4 + e[20]);

    float rt = 0.0f;
#pragma unroll
    for (int i = 0; i < NCLS; ++i) rt = (i == tgt) ? r[i] : rt;  // cndmask chain

    float pt  = __expf(rt - m) * fastrcp(s) + 1e-10f;
    float lpt = __logf(pt);
    float a   = (tgt == 0) ? 0.25f : 0.75f;
    float om  = 1.0f - pt;
    return -a * om * om * lpt;
}

template <bool PARTIALS>
__global__ __launch_bounds__(256, 5) void msl_main(
    const float* __restrict__ loc_data,
    const float* __restrict__ conf_data,
    const float* __restrict__ prop_loc_data,
    const float* __restrict__ prop_conf_data,
    const float* __restrict__ center_data,
    const float* __restrict__ priors,
    const float* __restrict__ targets,
    double* __restrict__ ws,
    int K, int nblk)
{
    __shared__ float s_red[6 * 4];

    const int b    = blockIdx.y;
    const int tid  = threadIdx.x;
    const int lane = tid & 63;
    const int w    = tid >> 6;
    const int k    = blockIdx.x * 256 + tid;
    const size_t idx = (size_t)b * K + k;

    // ---- all loads issued up front: 4 smalls + 12 row-loads to VGPR ----
    const float  c   = priors[k];
    const float2 loc = ((const float2*)loc_data)[idx];
    const float2 plo = ((const float2*)prop_loc_data)[idx];
    const float  x   = center_data[idx];

    float rc[NCLS], rp[NCLS];
    load_row21(conf_data      + idx * NCLS, rc);
    load_row21(prop_conf_data + idx * NCLS, rp);

    // ---- match: argmin over 32 GTs via scalar (SGPR) targets ----
    // area = inside ? (t1-t0)*256 : 512  (inside length < 52 < 512)
    const float* tgs = targets + (size_t)b * (NGT * 3);
    float bestA = 3.0e38f;
    float bT0 = 0.0f, bT1 = 0.0f, bLb = 0.0f;
#pragma unroll
    for (int n = 0; n < NGT; ++n) {
        const float t0n = tgs[3 * n];
        const float t1n = tgs[3 * n + 1];
        const float lbn = tgs[3 * n + 2];
        const bool outside = (t0n > c) || (t1n < c);
        const float cand = outside ? MAXN : (t1n - t0n) * CLIPLEN;
        const bool better = cand < bestA;   // strict: first occurrence wins
        bestA = better ? cand : bestA;
        bT0   = better ? t0n  : bT0;
        bT1   = better ? t1n  : bT1;
        bLb   = better ? lbn  : bLb;
    }
    const float tl = (c - bT0) * CLIPLEN;
    const float tr = (bT1 - c) * CLIPLEN;
    const int conf_t = (bestA >= MAXN) ? 0 : (int)bLb;

    const float pl = loc.x, pr = loc.y;

    // ---- IoU(loc_data, loc_t) ----
    const float inter = fminf(pl, tl) + fminf(pr, tr);
    const float uni   = pl + pr + tl + tr - inter;
    const float iou   = inter * fastrcp(fmaxf(uni, FEPS));

    const int prop_conf_t = (iou < 0.5f) ? 0 : conf_t;
    const float posf = (conf_t > 0) ? 1.0f : 0.0f;
    const float ppf  = (prop_conf_t > 0) ? 1.0f : 0.0f;

    // ---- loss_l: GIoU ----
    const float ac   = fmaxf(pl, tl) + fmaxf(pr, tr);
    const float giou = iou - (ac - uni) * fastrcp(fmaxf(ac, FEPS));
    const float v_ll = (1.0f - giou) * posf;

    // ---- loss_prop_l ----
    const float prop_w = pl + pr;
    const float inv_hw = 2.0f * fastrcp(prop_w);
    const float plt0 = (tl - pl) * inv_hw;
    const float plt1 = (tr - pr) * inv_hw;
    const float v_lpl = (fabsf(plo.x - plt0) + fabsf(plo.y - plt1)) * ppf;

    // ---- loss_ct ----
    const float cur0 = 0.5f * prop_w * plo.x + pl;
    const float cur1 = 0.5f * prop_w * plo.y + pr;
    const float in2  = fminf(cur0, tl) + fminf(cur1, tr);
    const float un2  = cur0 + cur1 + tl + tr - in2;
    const float iou2 = fmaxf(in2 * fastrcp(fmaxf(un2, FEPS)), 0.0f);
    const float ebx  = __expf(-fabsf(x));
    const float bce  = fmaxf(x, 0.0f) - x * iou2 + __logf(1.0f + ebx);
    const float v_ct = bce * posf;

    // ---- focal terms from registers ----
    const float v_lc  = focal_reg(rc, conf_t);
    const float v_lpc = focal_reg(rp, prop_conf_t);

    // ---- block reduction (counts packed: posf + 4096*ppf) ----
    float vals[6] = { v_ll, v_lc, v_lpl, v_lpc, v_ct, posf + 4096.0f * ppf };
#pragma unroll
    for (int i = 0; i < 6; ++i) {
        float v = vals[i];
#pragma unroll
        for (int off = 32; off > 0; off >>= 1) v += __shfl_xor(v, off);
        if (lane == 0) s_red[i * 4 + w] = v;
    }
    __syncthreads();
    if (tid == 0) {
        const int blk = blockIdx.y * gridDim.x + blockIdx.x;
#pragma unroll
        for (int i = 0; i < 5; ++i) {
            double s = (double)s_red[i * 4 + 0] + (double)s_red[i * 4 + 1]
                     + (double)s_red[i * 4 + 2] + (double)s_red[i * 4 + 3];
            if (PARTIALS) ws[(size_t)i * nblk + blk] = s;
            else          atomicAdd(&ws[i], s);
        }
        double ct = (double)s_red[5 * 4 + 0] + (double)s_red[5 * 4 + 1]
                  + (double)s_red[5 * 4 + 2] + (double)s_red[5 * 4 + 3];
        double pp = floor(ct / 4096.0);   // prop_pos count (exact)
        double ps = ct - 4096.0 * pp;     // pos count (exact)
        if (PARTIALS) {
            ws[(size_t)5 * nblk + blk] = ps;
            ws[(size_t)6 * nblk + blk] = pp;
        } else {
            atomicAdd(&ws[5], ps);
            atomicAdd(&ws[6], pp);
        }
    }
}

// Single-block deterministic reduction of per-block partials -> 5 outputs.
__global__ __launch_bounds__(256) void msl_reduce(
    const double* __restrict__ p, int nblk, float* __restrict__ out)
{
    __shared__ double s_acc[7];
    __shared__ double s_w[4];
    const int tid  = threadIdx.x;
    const int lane = tid & 63;
    const int w    = tid >> 6;

    for (int i = 0; i < 7; ++i) {
        double v = 0.0;
        for (int j = tid; j < nblk; j += 256) v += p[(size_t)i * nblk + j];
#pragma unroll
        for (int off = 32; off > 0; off >>= 1) v += __shfl_xor(v, off);
        if (lane == 0) s_w[w] = v;
        __syncthreads();
        if (tid == 0) s_acc[i] = s_w[0] + s_w[1] + s_w[2] + s_w[3];
        __syncthreads();
    }
    if (tid == 0) {
        const double N  = fmax(s_acc[5], 1.0);
        const double PN = fmax(s_acc[6], 1.0);
        out[0] = (float)(s_acc[0] / N);   // loss_l
        out[1] = (float)(s_acc[1] / N);   // loss_c
        out[2] = (float)(s_acc[2] / PN);  // loss_prop_l
        out[3] = (float)(s_acc[3] / PN);  // loss_prop_c
        out[4] = (float)(s_acc[4] / N);   // loss_ct
    }
}

__global__ void msl_finalize(const double* __restrict__ acc, float* __restrict__ out) {
    const double N  = fmax(acc[5], 1.0);
    const double PN = fmax(acc[6], 1.0);
    out[0] = (float)(acc[0] / N);
    out[1] = (float)(acc[1] / N);
    out[2] = (float)(acc[2] / PN);
    out[3] = (float)(acc[3] / PN);
    out[4] = (float)(acc[4] / N);
}

extern "C" void kernel_launch(void* const* d_in, const int* in_sizes, int n_in,
                              void* d_out, int out_size, void* d_ws, size_t ws_size,
                              hipStream_t stream) {
    const float* loc_data       = (const float*)d_in[0];
    const float* conf_data      = (const float*)d_in[1];
    const float* prop_loc_data  = (const float*)d_in[2];
    const float* prop_conf_data = (const float*)d_in[3];
    const float* center_data    = (const float*)d_in[4];
    const float* priors         = (const float*)d_in[5];
    const float* targets        = (const float*)d_in[6];
    float* out = (float*)d_out;

    const int K = in_sizes[5];            // priors: (K, 1)
    const int B = in_sizes[6] / (NGT * 3);
    const int nblk = (K / 256) * B;

    double* ws = (double*)d_ws;
    dim3 grid(K / 256, B);

    if (ws_size >= (size_t)7 * nblk * sizeof(double)) {
        // contention-free partials + deterministic reduce (no atomics)
        msl_main<true><<<grid, 256, 0, stream>>>(loc_data, conf_data, prop_loc_data,
                                                 prop_conf_data, center_data, priors,
                                                 targets, ws, K, nblk);
        msl_reduce<<<1, 256, 0, stream>>>(ws, nblk, out);
    } else {
        hipMemsetAsync(ws, 0, 7 * sizeof(double), stream);
        msl_main<false><<<grid, 256, 0, stream>>>(loc_data, conf_data, prop_loc_data,
                                                  prop_conf_data, center_data, priors,
                                                  targets, ws, K, nblk);
        msl_finalize<<<1, 1, 0, stream>>>(ws, out);
    }
}

// Round 10
// 68.572 us; speedup vs baseline: 2.5418x; 1.0066x over previous
//
#include <hip/hip_runtime.h>
#include <math.h>

#define NCLS 21
#define NGT 32
#define CLIPLEN 256.0f
#define MAXN 512.0f
#define FEPS 1.1920928955078125e-07f

// partial layout in d_ws (doubles): p[i * nblk + blk], i in 0..6
// i: 0 loss_l, 1 loss_c, 2 loss_prop_l, 3 loss_prop_c, 4 loss_ct, 5 pos, 6 prop_pos

typedef float f32x4 __attribute__((ext_vector_type(4)));
typedef f32x4 f32x4_u __attribute__((aligned(4)));   // dword-aligned vector load

__device__ __forceinline__ float fastrcp(float x) { return __builtin_amdgcn_rcpf(x); }

__device__ __forceinline__ void load_row21(const float* __restrict__ p, float* r) {
    // 5 x dwordx4 + 1 x dword, 4-byte aligned (hw supports dword-aligned x4)
    f32x4 v0 = *(const f32x4_u*)(p + 0);
    f32x4 v1 = *(const f32x4_u*)(p + 4);
    f32x4 v2 = *(const f32x4_u*)(p + 8);
    f32x4 v3 = *(const f32x4_u*)(p + 12);
    f32x4 v4 = *(const f32x4_u*)(p + 16);
    float  v5 = p[20];
    r[0]=v0.x; r[1]=v0.y; r[2]=v0.z; r[3]=v0.w;
    r[4]=v1.x; r[5]=v1.y; r[6]=v1.z; r[7]=v1.w;
    r[8]=v2.x; r[9]=v2.y; r[10]=v2.z; r[11]=v2.w;
    r[12]=v3.x; r[13]=v3.y; r[14]=v3.z; r[15]=v3.w;
    r[16]=v4.x; r[17]=v4.y; r[18]=v4.z; r[19]=v4.w;
    r[20]=v5;
}

// focal from register row; rt extracted with compile-time-index selects
__device__ __forceinline__ float focal_reg(const float* r, int tgt) {
    float m0 = fmaxf(fmaxf(r[0],  r[1]),  r[2]);
    float m1 = fmaxf(fmaxf(r[3],  r[4]),  r[5]);
    float m2 = fmaxf(fmaxf(r[6],  r[7]),  r[8]);
    float m3 = fmaxf(fmaxf(r[9],  r[10]), r[11]);
    float m4 = fmaxf(fmaxf(r[12], r[13]), r[14]);
    float m5 = fmaxf(fmaxf(r[15], r[16]), r[17]);
    float m6 = fmaxf(fmaxf(r[18], r[19]), r[20]);
    float ma = fmaxf(fmaxf(m0, m1), m2);
    float mb = fmaxf(fmaxf(m3, m4), m5);
    float m  = fmaxf(fmaxf(ma, mb), m6);

    float e[NCLS];
#pragma unroll
    for (int i = 0; i < NCLS; ++i) e[i] = __expf(r[i] - m);
    float s0 = (e[0] + e[1])  + (e[2] + e[3]);
    float s1 = (e[4] + e[5])  + (e[6] + e[7]);
    float s2 = (e[8] + e[9])  + (e[10] + e[11]);
    float s3 = (e[12] + e[13]) + (e[14] + e[15]);
    float s4 = (e[16] + e[17]) + (e[18] + e[19]);
    float s  = ((s0 + s1) + (s2 + s3)) + (s4 + e[20]);

    float rt = 0.0f;
#pragma unroll
    for (int i = 0; i < NCLS; ++i) rt = (i == tgt) ? r[i] : rt;  // cndmask chain

    float pt  = __expf(rt - m) * fastrcp(s) + 1e-10f;
    float lpt = __logf(pt);
    float a   = (tgt == 0) ? 0.25f : 0.75f;
    float om  = 1.0f - pt;
    return -a * om * om * lpt;
}

template <bool PARTIALS, bool SWZ>
__global__ __launch_bounds__(256, 5) void msl_main(
    const float* __restrict__ loc_data,
    const float* __restrict__ conf_data,
    const float* __restrict__ prop_loc_data,
    const float* __restrict__ prop_conf_data,
    const float* __restrict__ center_data,
    const float* __restrict__ priors,
    const float* __restrict__ targets,
    double* __restrict__ ws,
    int K, int nblk)
{
    __shared__ float s_red[6 * 4];

    // ---- chunked XCD swizzle: consecutive hw blocks round-robin XCDs; remap
    // so each XCD owns ONE contiguous (b-major) address window -> few, long
    // DRAM streams per XCD instead of thousands of interleaved 21.5KB bursts.
    const int nwg = nblk;                 // (K/256)*B
    int lin;
    if (SWZ) {
        const int wg = blockIdx.x;
        lin = (wg & 7) * (nwg >> 3) + (wg >> 3);
    } else {
        lin = blockIdx.x;
    }
    const int kxPerB = K >> 8;            // K/256
    const int b  = lin / kxPerB;
    const int kx = lin - b * kxPerB;

    const int tid  = threadIdx.x;
    const int lane = tid & 63;
    const int w    = tid >> 6;
    const int k    = kx * 256 + tid;
    const size_t idx = (size_t)b * K + k;

    // ---- all loads issued up front: 4 smalls + 12 row-loads to VGPR ----
    const float  c   = priors[k];
    const float2 loc = ((const float2*)loc_data)[idx];
    const float2 plo = ((const float2*)prop_loc_data)[idx];
    const float  x   = center_data[idx];

    float rc[NCLS], rp[NCLS];
    load_row21(conf_data      + idx * NCLS, rc);
    load_row21(prop_conf_data + idx * NCLS, rp);

    // ---- match: argmin over 32 GTs via scalar (SGPR) targets ----
    // area = inside ? (t1-t0)*256 : 512  (inside length < 52 < 512)
    const float* tgs = targets + (size_t)b * (NGT * 3);
    float bestA = 3.0e38f;
    float bT0 = 0.0f, bT1 = 0.0f, bLb = 0.0f;
#pragma unroll
    for (int n = 0; n < NGT; ++n) {
        const float t0n = tgs[3 * n];
        const float t1n = tgs[3 * n + 1];
        const float lbn = tgs[3 * n + 2];
        const bool outside = (t0n > c) || (t1n < c);
        const float cand = outside ? MAXN : (t1n - t0n) * CLIPLEN;
        const bool better = cand < bestA;   // strict: first occurrence wins
        bestA = better ? cand : bestA;
        bT0   = better ? t0n  : bT0;
        bT1   = better ? t1n  : bT1;
        bLb   = better ? lbn  : bLb;
    }
    const float tl = (c - bT0) * CLIPLEN;
    const float tr = (bT1 - c) * CLIPLEN;
    const int conf_t = (bestA >= MAXN) ? 0 : (int)bLb;

    const float pl = loc.x, pr = loc.y;

    // ---- IoU(loc_data, loc_t) ----
    const float inter = fminf(pl, tl) + fminf(pr, tr);
    const float uni   = pl + pr + tl + tr - inter;
    const float iou   = inter * fastrcp(fmaxf(uni, FEPS));

    const int prop_conf_t = (iou < 0.5f) ? 0 : conf_t;
    const float posf = (conf_t > 0) ? 1.0f : 0.0f;
    const float ppf  = (prop_conf_t > 0) ? 1.0f : 0.0f;

    // ---- loss_l: GIoU ----
    const float ac   = fmaxf(pl, tl) + fmaxf(pr, tr);
    const float giou = iou - (ac - uni) * fastrcp(fmaxf(ac, FEPS));
    const float v_ll = (1.0f - giou) * posf;

    // ---- loss_prop_l ----
    const float prop_w = pl + pr;
    const float inv_hw = 2.0f * fastrcp(prop_w);
    const float plt0 = (tl - pl) * inv_hw;
    const float plt1 = (tr - pr) * inv_hw;
    const float v_lpl = (fabsf(plo.x - plt0) + fabsf(plo.y - plt1)) * ppf;

    // ---- loss_ct ----
    const float cur0 = 0.5f * prop_w * plo.x + pl;
    const float cur1 = 0.5f * prop_w * plo.y + pr;
    const float in2  = fminf(cur0, tl) + fminf(cur1, tr);
    const float un2  = cur0 + cur1 + tl + tr - in2;
    const float iou2 = fmaxf(in2 * fastrcp(fmaxf(un2, FEPS)), 0.0f);
    const float ebx  = __expf(-fabsf(x));
    const float bce  = fmaxf(x, 0.0f) - x * iou2 + __logf(1.0f + ebx);
    const float v_ct = bce * posf;

    // ---- focal terms from registers ----
    const float v_lc  = focal_reg(rc, conf_t);
    const float v_lpc = focal_reg(rp, prop_conf_t);

    // ---- block reduction (counts packed: posf + 4096*ppf) ----
    float vals[6] = { v_ll, v_lc, v_lpl, v_lpc, v_ct, posf + 4096.0f * ppf };
#pragma unroll
    for (int i = 0; i < 6; ++i) {
        float v = vals[i];
#pragma unroll
        for (int off = 32; off > 0; off >>= 1) v += __shfl_xor(v, off);
        if (lane == 0) s_red[i * 4 + w] = v;
    }
    __syncthreads();
    if (tid == 0) {
        const int blk = lin;              // same partial slot as pre-swizzle
#pragma unroll
        for (int i = 0; i < 5; ++i) {
            double s = (double)s_red[i * 4 + 0] + (double)s_red[i * 4 + 1]
                     + (double)s_red[i * 4 + 2] + (double)s_red[i * 4 + 3];
            if (PARTIALS) ws[(size_t)i * nblk + blk] = s;
            else          atomicAdd(&ws[i], s);
        }
        double ct = (double)s_red[5 * 4 + 0] + (double)s_red[5 * 4 + 1]
                  + (double)s_red[5 * 4 + 2] + (double)s_red[5 * 4 + 3];
        double pp = floor(ct / 4096.0);   // prop_pos count (exact)
        double ps = ct - 4096.0 * pp;     // pos count (exact)
        if (PARTIALS) {
            ws[(size_t)5 * nblk + blk] = ps;
            ws[(size_t)6 * nblk + blk] = pp;
        } else {
            atomicAdd(&ws[5], ps);
            atomicAdd(&ws[6], pp);
        }
    }
}

// Single-block deterministic reduction of per-block partials -> 5 outputs.
__global__ __launch_bounds__(256) void msl_reduce(
    const double* __restrict__ p, int nblk, float* __restrict__ out)
{
    __shared__ double s_acc[7];
    __shared__ double s_w[4];
    const int tid  = threadIdx.x;
    const int lane = tid & 63;
    const int w    = tid >> 6;

    for (int i = 0; i < 7; ++i) {
        double v = 0.0;
        for (int j = tid; j < nblk; j += 256) v += p[(size_t)i * nblk + j];
#pragma unroll
        for (int off = 32; off > 0; off >>= 1) v += __shfl_xor(v, off);
        if (lane == 0) s_w[w] = v;
        __syncthreads();
        if (tid == 0) s_acc[i] = s_w[0] + s_w[1] + s_w[2] + s_w[3];
        __syncthreads();
    }
    if (tid == 0) {
        const double N  = fmax(s_acc[5], 1.0);
        const double PN = fmax(s_acc[6], 1.0);
        out[0] = (float)(s_acc[0] / N);   // loss_l
        out[1] = (float)(s_acc[1] / N);   // loss_c
        out[2] = (float)(s_acc[2] / PN);  // loss_prop_l
        out[3] = (float)(s_acc[3] / PN);  // loss_prop_c
        out[4] = (float)(s_acc[4] / N);   // loss_ct
    }
}

__global__ void msl_finalize(const double* __restrict__ acc, float* __restrict__ out) {
    const double N  = fmax(acc[5], 1.0);
    const double PN = fmax(acc[6], 1.0);
    out[0] = (float)(acc[0] / N);
    out[1] = (float)(acc[1] / N);
    out[2] = (float)(acc[2] / PN);
    out[3] = (float)(acc[3] / PN);
    out[4] = (float)(acc[4] / N);
}

extern "C" void kernel_launch(void* const* d_in, const int* in_sizes, int n_in,
                              void* d_out, int out_size, void* d_ws, size_t ws_size,
                              hipStream_t stream) {
    const float* loc_data       = (const float*)d_in[0];
    const float* conf_data      = (const float*)d_in[1];
    const float* prop_loc_data  = (const float*)d_in[2];
    const float* prop_conf_data = (const float*)d_in[3];
    const float* center_data    = (const float*)d_in[4];
    const float* priors         = (const float*)d_in[5];
    const float* targets        = (const float*)d_in[6];
    float* out = (float*)d_out;

    const int K = in_sizes[5];            // priors: (K, 1)
    const int B = in_sizes[6] / (NGT * 3);
    const int nblk = (K / 256) * B;

    double* ws = (double*)d_ws;
    const bool swz = (nblk % 8) == 0;
    dim3 grid(nblk);

    if (ws_size >= (size_t)7 * nblk * sizeof(double)) {
        if (swz)
            msl_main<true, true><<<grid, 256, 0, stream>>>(loc_data, conf_data,
                prop_loc_data, prop_conf_data, center_data, priors, targets, ws, K, nblk);
        else
            msl_main<true, false><<<grid, 256, 0, stream>>>(loc_data, conf_data,
                prop_loc_data, prop_conf_data, center_data, priors, targets, ws, K, nblk);
        msl_reduce<<<1, 256, 0, stream>>>(ws, nblk, out);
    } else {
        hipMemsetAsync(ws, 0, 7 * sizeof(double), stream);
        if (swz)
            msl_main<false, true><<<grid, 256, 0, stream>>>(loc_data, conf_data,
                prop_loc_data, prop_conf_data, center_data, priors, targets, ws, K, nblk);
        else
            msl_main<false, false><<<grid, 256, 0, stream>>>(loc_data, conf_data,
                prop_loc_data, prop_conf_data, center_data, priors, targets, ws, K, nblk);
        msl_finalize<<<1, 1, 0, stream>>>(ws, out);
    }
}